// Round 16
// baseline (1229.722 us; speedup 1.0000x reference)
//
#include <hip/hip_runtime.h>
#include <cstdint>
#include <cstddef>

#define NB 32      // batch
#define NT 2000    // timesteps
#define NI 256     // input dim
#define NN 512     // neurons
#define M_TOT (NB * NT)   // 64000 rows of the input GEMM
#define DS 8       // LDS cur ring slots

typedef float f32x4 __attribute__((ext_vector_type(4)));

// ---------------- transpose R -> Rt (Rt[j][n] = R[n][j]) ----------------
__global__ void transpose_R(const float* __restrict__ R, float* __restrict__ Rt) {
    int idx = blockIdx.x * blockDim.x + threadIdx.x;
    if (idx >= NN * NN) return;
    int j = idx >> 9;
    int n = idx & (NN - 1);
    Rt[idx] = R[n * NN + j];
}

// ---------------- GEMM: cur[m][n] = sum_k x[m][k]*W[n][k] + bias[n] ----------------
#define GBM 128
#define GBN 128
#define GBK 16
__global__ __launch_bounds__(256) void gemm_xw(const float* __restrict__ A,
                                               const float* __restrict__ Wt,
                                               const float* __restrict__ bias,
                                               float* __restrict__ C) {
    __shared__ float As[GBK][GBM];
    __shared__ float Bs[GBK][GBN];
    const int tid = threadIdx.x;
    const int bm = blockIdx.x * GBM;
    const int bn = blockIdx.y * GBN;
    const int tx = tid & 15, ty = tid >> 4;
    const int lrow = tid >> 1;
    const int lk = (tid & 1) * 8;
    float acc[8][8] = {};
    const float* Arow = A + (size_t)(bm + lrow) * NI + lk;
    const float* Brow = Wt + (size_t)(bn + lrow) * NI + lk;
    for (int k0 = 0; k0 < NI; k0 += GBK) {
        float4 a0 = *(const float4*)(Arow + k0);
        float4 a1 = *(const float4*)(Arow + k0 + 4);
        float4 b0 = *(const float4*)(Brow + k0);
        float4 b1 = *(const float4*)(Brow + k0 + 4);
        __syncthreads();
        As[lk + 0][lrow] = a0.x; As[lk + 1][lrow] = a0.y;
        As[lk + 2][lrow] = a0.z; As[lk + 3][lrow] = a0.w;
        As[lk + 4][lrow] = a1.x; As[lk + 5][lrow] = a1.y;
        As[lk + 6][lrow] = a1.z; As[lk + 7][lrow] = a1.w;
        Bs[lk + 0][lrow] = b0.x; Bs[lk + 1][lrow] = b0.y;
        Bs[lk + 2][lrow] = b0.z; Bs[lk + 3][lrow] = b0.w;
        Bs[lk + 4][lrow] = b1.x; Bs[lk + 5][lrow] = b1.y;
        Bs[lk + 6][lrow] = b1.z; Bs[lk + 7][lrow] = b1.w;
        __syncthreads();
        #pragma unroll
        for (int k = 0; k < GBK; ++k) {
            float4 av0 = *(const float4*)&As[k][ty * 8];
            float4 av1 = *(const float4*)&As[k][ty * 8 + 4];
            float4 bv0 = *(const float4*)&Bs[k][tx * 8];
            float4 bv1 = *(const float4*)&Bs[k][tx * 8 + 4];
            float a_[8] = {av0.x, av0.y, av0.z, av0.w, av1.x, av1.y, av1.z, av1.w};
            float b_[8] = {bv0.x, bv0.y, bv0.z, bv0.w, bv1.x, bv1.y, bv1.z, bv1.w};
            #pragma unroll
            for (int i = 0; i < 8; ++i)
                #pragma unroll
                for (int j = 0; j < 8; ++j)
                    acc[i][j] += a_[i] * b_[j];
        }
    }
    #pragma unroll
    for (int i = 0; i < 8; ++i) {
        const int row = bm + ty * 8 + i;
        #pragma unroll
        for (int j = 0; j < 8; ++j) {
            const int col = bn + tx * 8 + j;
            C[(size_t)row * NN + col] = acc[i][j] + bias[col];
        }
    }
}

// ---------------- producer/consumer LIF scan: 2 waves per batch element ----------------
// Round-12 structure plus: (a) conflict-free LDS ring layout [slot][2][256]
// (16B lane stride, was 32B -> 1.5M bank-conflict cycles); (b) gather head
// loads issued at the END of the previous step (masks known after ballots),
// staying in flight across the raw s_barrier -- vmcnt(0) pays only residual
// latency; (c) 2-deep heads (first TWO bits per mask) kill the serial tails.
// Accumulation order unchanged (e=0..7, ascending bits): bit-identical.

#define UPD(C_, R_, DU_, ODU_, DW_, ODW_, A_, B_, U_, W_, Z_) do {               \
    float cc_   = __fadd_rn((C_), (R_));                                         \
    float unew_ = __fadd_rn(__fmul_rn((DU_), (U_)),                              \
                            __fmul_rn((ODU_), __fsub_rn(cc_, (W_))));            \
    float zn_   = (__fsub_rn(unew_, 1.0f) > 0.0f) ? 1.0f : 0.0f;                 \
    float s_    = __fadd_rn(__fmul_rn((A_), (U_)), __fmul_rn((B_), (Z_)));       \
    float wnew_ = __fadd_rn(__fmul_rn((DW_), (W_)),                              \
                            __fmul_rn(__fmul_rn((ODW_), s_), 120.0f));           \
    (U_) = __fmul_rn(unew_, __fsub_rn(1.0f, zn_));                               \
    (W_) = wnew_;                                                                \
    (Z_) = zn_;                                                                  \
} while (0)

#define HLOAD(DA, DB, PTR)                                                       \
    asm volatile("global_load_dwordx4 %0, %2, off\n\t"                           \
                 "global_load_dwordx4 %1, %2, off offset:16"                     \
                 : "=&v"(DA), "=&v"(DB) : "v"(PTR))

__global__ __launch_bounds__(128, 1) void scan_pc(const float* __restrict__ cur,
        const float* __restrict__ Rm,   // Rt: Rm[j][n] = R[n][j]
        const float* __restrict__ du_g, const float* __restrict__ dw_g,
        const float* __restrict__ a_g, const float* __restrict__ b_g,
        float* __restrict__ out) {
    __shared__ float curlds[DS][2][256];   // 16 KB ring; 16B lane stride per half
    const int tid = threadIdx.x;
    const int lane = tid & 63;
    const int b = blockIdx.x;
    const float* curb = cur + (size_t)b * NT * NN;

    if (tid >= 64) {
        // ================= producer wave =================
        const int off = lane << 3;          // global: 8 contiguous floats per lane
        const int lo4 = lane << 2;          // LDS: 16B stride, conflict-free
        float4 q0a, q0b, q1a, q1b, q2a, q2b, q3a, q3b;
        #define PLOAD(QA, QB, STEP) do {                                          \
            const float* p_ = curb + (size_t)(STEP) * NN + off;                   \
            QA = *(const float4*)p_; QB = *(const float4*)(p_ + 4);               \
        } while (0)
        #define PSTORE(QA, QB, STEP) do {                                         \
            int sl_ = (STEP) & (DS - 1);                                          \
            *(float4*)&curlds[sl_][0][lo4] = QA;                                  \
            *(float4*)&curlds[sl_][1][lo4] = QB;                                  \
        } while (0)
        PLOAD(q0a, q0b, 0); PLOAD(q1a, q1b, 1); PLOAD(q2a, q2b, 2); PLOAD(q3a, q3b, 3);
        PSTORE(q0a, q0b, 0); PSTORE(q1a, q1b, 1); PSTORE(q2a, q2b, 2);
        PLOAD(q0a, q0b, 4); PLOAD(q1a, q1b, 5); PLOAD(q2a, q2b, 6);
        #define PSTEP(QA, QB, T) do {                                             \
            int ws_ = (T) + 3; if (ws_ > NT - 1) ws_ = NT - 1;                    \
            int ls_ = (T) + 7; if (ls_ > NT - 1) ls_ = NT - 1;                    \
            PSTORE(QA, QB, ws_);                                                  \
            PLOAD(QA, QB, ls_);                                                   \
            asm volatile("s_waitcnt lgkmcnt(0)" ::: "memory");                    \
            __builtin_amdgcn_s_barrier();                                         \
        } while (0)
        for (int t = 0; t < NT; t += 4) {
            PSTEP(q3a, q3b, t + 0);
            PSTEP(q0a, q0b, t + 1);
            PSTEP(q1a, q1b, t + 2);
            PSTEP(q2a, q2b, t + 3);
        }
        #undef PSTEP
        #undef PSTORE
        #undef PLOAD
    } else {
        // ================= consumer wave =================
        const int n0 = lane << 3;
        const int lo4 = lane << 2;

        const float4 du0 = *(const float4*)(du_g + n0);
        const float4 du1 = *(const float4*)(du_g + n0 + 4);
        const float4 dw0 = *(const float4*)(dw_g + n0);
        const float4 dw1 = *(const float4*)(dw_g + n0 + 4);
        const float4 an0 = *(const float4*)(a_g + n0);
        const float4 an1 = *(const float4*)(a_g + n0 + 4);
        const float4 bn0 = *(const float4*)(b_g + n0);
        const float4 bn1 = *(const float4*)(b_g + n0 + 4);
        const float4 odu0 = {1.0f - du0.x, 1.0f - du0.y, 1.0f - du0.z, 1.0f - du0.w};
        const float4 odu1 = {1.0f - du1.x, 1.0f - du1.y, 1.0f - du1.z, 1.0f - du1.w};
        const float4 odw0 = {1.0f - dw0.x, 1.0f - dw0.y, 1.0f - dw0.z, 1.0f - dw0.w};
        const float4 odw1 = {1.0f - dw1.x, 1.0f - dw1.y, 1.0f - dw1.z, 1.0f - dw1.w};

        float4 u0 = {0,0,0,0}, u1 = {0,0,0,0};
        float4 w0 = {0,0,0,0}, w1 = {0,0,0,0};
        float4 z0 = {0,0,0,0}, z1 = {0,0,0,0};
        unsigned long long m0=0,m1=0,m2=0,m3=0,m4=0,m5=0,m6=0,m7=0;

        // 2-deep head destinations: hXa/hXb = first-bit row, hXc/hXd = second-bit
        f32x4 h0a,h0b,h0c,h0d, h1a,h1b,h1c,h1d, h2a,h2b,h2c,h2d, h3a,h3b,h3c,h3d;
        f32x4 h4a,h4b,h4c,h4d, h5a,h5b,h5c,h5d, h6a,h6b,h6c,h6d, h7a,h7b,h7c,h7d;

        float* outp = out + (size_t)b * NT * NN + n0;

        for (int t = 0; t < NT; ++t) {
            __builtin_amdgcn_s_barrier();
            __builtin_amdgcn_sched_barrier(0);
            asm volatile("" ::: "memory");
            const int slot = t & (DS - 1);
            float4 c0 = *(const float4*)&curlds[slot][0][lo4];
            float4 c1 = *(const float4*)&curlds[slot][1][lo4];

            float4 r0 = {0,0,0,0}, r1 = {0,0,0,0};
            if (m0 | m1 | m2 | m3 | m4 | m5 | m6 | m7) {
                // loads were issued at the end of step t-1; only residual wait here
                asm volatile("s_waitcnt vmcnt(0)" ::: "memory");
                __builtin_amdgcn_sched_barrier(0);

                #define ACC(QA, QB) do {                                          \
                    r0.x = __fadd_rn(r0.x, (QA).x); r0.y = __fadd_rn(r0.y, (QA).y);\
                    r0.z = __fadd_rn(r0.z, (QA).z); r0.w = __fadd_rn(r0.w, (QA).w);\
                    r1.x = __fadd_rn(r1.x, (QB).x); r1.y = __fadd_rn(r1.y, (QB).y);\
                    r1.z = __fadd_rn(r1.z, (QB).z); r1.w = __fadd_rn(r1.w, (QB).w);\
                } while (0)
                #define PROC2(MM, E, HA, HB, HC, HD) do {                         \
                    if (MM) {                                                     \
                        ACC(HA, HB);                                              \
                        unsigned long long g_ = (MM) & ((MM) - 1);                \
                        if (g_) {                                                 \
                            ACC(HC, HD);                                          \
                            g_ &= g_ - 1;                                         \
                            while (g_) {   /* very rare: 3rd+ bit in one mask */  \
                                int l_ = __builtin_ctzll(g_); g_ &= g_ - 1;       \
                                int j_ = (l_ << 3) + (E);                         \
                                const float* rp_ = Rm + ((size_t)j_ << 9) + n0;   \
                                float4 q0_ = *(const float4*)rp_;                 \
                                float4 q1_ = *(const float4*)(rp_ + 4);           \
                                ACC(q0_, q1_);                                    \
                            }                                                     \
                        }                                                         \
                    }                                                             \
                } while (0)
                PROC2(m0, 0, h0a, h0b, h0c, h0d);
                PROC2(m1, 1, h1a, h1b, h1c, h1d);
                PROC2(m2, 2, h2a, h2b, h2c, h2d);
                PROC2(m3, 3, h3a, h3b, h3c, h3d);
                PROC2(m4, 4, h4a, h4b, h4c, h4d);
                PROC2(m5, 5, h5a, h5b, h5c, h5d);
                PROC2(m6, 6, h6a, h6b, h6c, h6d);
                PROC2(m7, 7, h7a, h7b, h7c, h7d);
                #undef PROC2
                #undef ACC
            }

            UPD(c0.x, r0.x, du0.x, odu0.x, dw0.x, odw0.x, an0.x, bn0.x, u0.x, w0.x, z0.x);
            UPD(c0.y, r0.y, du0.y, odu0.y, dw0.y, odw0.y, an0.y, bn0.y, u0.y, w0.y, z0.y);
            UPD(c0.z, r0.z, du0.z, odu0.z, dw0.z, odw0.z, an0.z, bn0.z, u0.z, w0.z, z0.z);
            UPD(c0.w, r0.w, du0.w, odu0.w, dw0.w, odw0.w, an0.w, bn0.w, u0.w, w0.w, z0.w);
            UPD(c1.x, r1.x, du1.x, odu1.x, dw1.x, odw1.x, an1.x, bn1.x, u1.x, w1.x, z1.x);
            UPD(c1.y, r1.y, du1.y, odu1.y, dw1.y, odw1.y, an1.y, bn1.y, u1.y, w1.y, z1.y);
            UPD(c1.z, r1.z, du1.z, odu1.z, dw1.z, odw1.z, an1.z, bn1.z, u1.z, w1.z, z1.z);
            UPD(c1.w, r1.w, du1.w, odu1.w, dw1.w, odw1.w, an1.w, bn1.w, u1.w, w1.w, z1.w);

            m0 = __ballot(z0.x > 0.5f);
            m1 = __ballot(z0.y > 0.5f);
            m2 = __ballot(z0.z > 0.5f);
            m3 = __ballot(z0.w > 0.5f);
            m4 = __ballot(z1.x > 0.5f);
            m5 = __ballot(z1.y > 0.5f);
            m6 = __ballot(z1.z > 0.5f);
            m7 = __ballot(z1.w > 0.5f);

            // ---- issue NEXT step's gather heads now; they fly across the barrier
            if (m0 | m1 | m2 | m3 | m4 | m5 | m6 | m7) {
                #define ISSUE2(MM, E, HA, HB, HC, HD) do {                        \
                    unsigned long long g1_ = (MM);                                \
                    unsigned long long g2_ = g1_ ? (g1_ & (g1_ - 1)) : 0ULL;      \
                    int ja_ = g1_ ? ((__builtin_ctzll(g1_) << 3) + (E)) : 0;      \
                    int jb_ = g2_ ? ((__builtin_ctzll(g2_) << 3) + (E)) : 0;      \
                    const float* pa_ = Rm + ((size_t)ja_ << 9) + n0;              \
                    const float* pb_ = Rm + ((size_t)jb_ << 9) + n0;              \
                    HLOAD(HA, HB, pa_);                                           \
                    HLOAD(HC, HD, pb_);                                           \
                } while (0)
                ISSUE2(m0, 0, h0a, h0b, h0c, h0d);
                ISSUE2(m1, 1, h1a, h1b, h1c, h1d);
                ISSUE2(m2, 2, h2a, h2b, h2c, h2d);
                ISSUE2(m3, 3, h3a, h3b, h3c, h3d);
                ISSUE2(m4, 4, h4a, h4b, h4c, h4d);
                ISSUE2(m5, 5, h5a, h5b, h5c, h5d);
                ISSUE2(m6, 6, h6a, h6b, h6c, h6d);
                ISSUE2(m7, 7, h7a, h7b, h7c, h7d);
                #undef ISSUE2
                __builtin_amdgcn_sched_barrier(0);
            }

            *(float4*)outp = z0;
            *(float4*)(outp + 4) = z1;
            outp += NN;
        }
    }
}

// ---------------- fallback scan (un-transposed R; only if workspace tiny) --------
__global__ __launch_bounds__(64) void scan_fallback(const float* __restrict__ cur,
        const float* __restrict__ Rm,
        const float* __restrict__ du_g, const float* __restrict__ dw_g,
        const float* __restrict__ a_g, const float* __restrict__ b_g,
        float* __restrict__ out) {
    const int lane = threadIdx.x & 63;
    const int b = blockIdx.x;
    const int n0 = lane << 3;
    const float4 du0 = *(const float4*)(du_g + n0);
    const float4 du1 = *(const float4*)(du_g + n0 + 4);
    const float4 dw0 = *(const float4*)(dw_g + n0);
    const float4 dw1 = *(const float4*)(dw_g + n0 + 4);
    const float4 an0 = *(const float4*)(a_g + n0);
    const float4 an1 = *(const float4*)(a_g + n0 + 4);
    const float4 bn0 = *(const float4*)(b_g + n0);
    const float4 bn1 = *(const float4*)(b_g + n0 + 4);
    const float4 odu0 = {1.0f - du0.x, 1.0f - du0.y, 1.0f - du0.z, 1.0f - du0.w};
    const float4 odu1 = {1.0f - du1.x, 1.0f - du1.y, 1.0f - du1.z, 1.0f - du1.w};
    const float4 odw0 = {1.0f - dw0.x, 1.0f - dw0.y, 1.0f - dw0.z, 1.0f - dw0.w};
    const float4 odw1 = {1.0f - dw1.x, 1.0f - dw1.y, 1.0f - dw1.z, 1.0f - dw1.w};
    float4 u0 = {0,0,0,0}, u1 = {0,0,0,0};
    float4 w0 = {0,0,0,0}, w1 = {0,0,0,0};
    float4 z0 = {0,0,0,0}, z1 = {0,0,0,0};
    unsigned long long m0=0,m1=0,m2=0,m3=0,m4=0,m5=0,m6=0,m7=0;
    const float* curp = cur + (size_t)b * NT * NN + n0;
    float* outp = out + (size_t)b * NT * NN + n0;
    for (int t = 0; t < NT; ++t) {
        float4 c0 = *(const float4*)(curp);
        float4 c1 = *(const float4*)(curp + 4);
        curp += NN;
        float4 r0 = {0,0,0,0}, r1 = {0,0,0,0};
        #define GATHER(MM, E) do {                                                \
            unsigned long long g_ = (MM);                                         \
            while (g_) {                                                          \
                int l_ = __builtin_ctzll(g_); g_ &= g_ - 1;                       \
                int j_ = (l_ << 3) + (E);                                         \
                float q0x_ = Rm[(size_t)(n0 + 0) * NN + j_];                      \
                float q0y_ = Rm[(size_t)(n0 + 1) * NN + j_];                      \
                float q0z_ = Rm[(size_t)(n0 + 2) * NN + j_];                      \
                float q0w_ = Rm[(size_t)(n0 + 3) * NN + j_];                      \
                float q1x_ = Rm[(size_t)(n0 + 4) * NN + j_];                      \
                float q1y_ = Rm[(size_t)(n0 + 5) * NN + j_];                      \
                float q1z_ = Rm[(size_t)(n0 + 6) * NN + j_];                      \
                float q1w_ = Rm[(size_t)(n0 + 7) * NN + j_];                      \
                r0.x = __fadd_rn(r0.x, q0x_); r0.y = __fadd_rn(r0.y, q0y_);       \
                r0.z = __fadd_rn(r0.z, q0z_); r0.w = __fadd_rn(r0.w, q0w_);       \
                r1.x = __fadd_rn(r1.x, q1x_); r1.y = __fadd_rn(r1.y, q1y_);       \
                r1.z = __fadd_rn(r1.z, q1z_); r1.w = __fadd_rn(r1.w, q1w_);       \
            }                                                                     \
        } while (0)
        GATHER(m0, 0); GATHER(m1, 1); GATHER(m2, 2); GATHER(m3, 3);
        GATHER(m4, 4); GATHER(m5, 5); GATHER(m6, 6); GATHER(m7, 7);
        #undef GATHER
        UPD(c0.x, r0.x, du0.x, odu0.x, dw0.x, odw0.x, an0.x, bn0.x, u0.x, w0.x, z0.x);
        UPD(c0.y, r0.y, du0.y, odu0.y, dw0.y, odw0.y, an0.y, bn0.y, u0.y, w0.y, z0.y);
        UPD(c0.z, r0.z, du0.z, odu0.z, dw0.z, odw0.z, an0.z, bn0.z, u0.z, w0.z, z0.z);
        UPD(c0.w, r0.w, du0.w, odu0.w, dw0.w, odw0.w, an0.w, bn0.w, u0.w, w0.w, z0.w);
        UPD(c1.x, r1.x, du1.x, odu1.x, dw1.x, odw1.x, an1.x, bn1.x, u1.x, w1.x, z1.x);
        UPD(c1.y, r1.y, du1.y, odu1.y, dw1.y, odw1.y, an1.y, bn1.y, u1.y, w1.y, z1.y);
        UPD(c1.z, r1.z, du1.z, odu1.z, dw1.z, odw1.z, an1.z, bn1.z, u1.z, w1.z, z1.z);
        UPD(c1.w, r1.w, du1.w, odu1.w, dw1.w, odw1.w, an1.w, bn1.w, u1.w, w1.w, z1.w);
        m0 = __ballot(z0.x > 0.5f);
        m1 = __ballot(z0.y > 0.5f);
        m2 = __ballot(z0.z > 0.5f);
        m3 = __ballot(z0.w > 0.5f);
        m4 = __ballot(z1.x > 0.5f);
        m5 = __ballot(z1.y > 0.5f);
        m6 = __ballot(z1.z > 0.5f);
        m7 = __ballot(z1.w > 0.5f);
        *(float4*)outp = z0;
        *(float4*)(outp + 4) = z1;
        outp += NN;
    }
}

extern "C" void kernel_launch(void* const* d_in, const int* in_sizes, int n_in,
                              void* d_out, int out_size, void* d_ws, size_t ws_size,
                              hipStream_t stream) {
    const float* x    = (const float*)d_in[0];
    const float* W    = (const float*)d_in[1];
    const float* bias = (const float*)d_in[2];
    const float* R    = (const float*)d_in[3];
    const float* du   = (const float*)d_in[4];
    const float* dw   = (const float*)d_in[5];
    const float* a    = (const float*)d_in[6];
    const float* b    = (const float*)d_in[7];
    float* out = (float*)d_out;

    const size_t curBytes = (size_t)M_TOT * NN * sizeof(float);   // 131 MB
    const size_t rtBytes  = (size_t)NN * NN * sizeof(float);      // 1 MB
    float* Rt  = nullptr;
    float* cur;
    if (ws_size >= rtBytes + curBytes) {
        Rt  = (float*)d_ws;
        cur = (float*)d_ws + (size_t)NN * NN;
    } else if (ws_size >= rtBytes) {
        Rt  = (float*)d_ws;
        cur = out;
    } else {
        cur = out;
    }

    if (Rt) {
        transpose_R<<<(NN * NN + 255) / 256, 256, 0, stream>>>(R, Rt);
    }
    dim3 ggrid(M_TOT / GBM, NN / GBN);
    gemm_xw<<<ggrid, 256, 0, stream>>>(x, W, bias, cur);
    if (Rt) {
        scan_pc<<<NB, 128, 0, stream>>>(cur, Rt, du, dw, a, b, out);
    } else {
        scan_fallback<<<NB, 64, 0, stream>>>(cur, R, du, dw, a, b, out);
    }
}